// Round 2
// baseline (2940.733 us; speedup 1.0000x reference)
//
#include <hip/hip_runtime.h>

// Tsit5 coefficients (b7 = 0 -> 6 stages)
__device__ constexpr float cA21 = 0.161f;
__device__ constexpr float cA31 = -0.008480655492356989f, cA32 = 0.335480655492357f;
__device__ constexpr float cA41 = 2.8971530571054935f,  cA42 = -6.359448489975075f,  cA43 = 4.3622954328695815f;
__device__ constexpr float cA51 = 5.325864828439257f,   cA52 = -11.748883564062828f, cA53 = 7.4955393428898365f, cA54 = -0.09249506636175525f;
__device__ constexpr float cA61 = 5.86145544294642f,    cA62 = -12.92096931784711f,  cA63 = 8.159367898576159f,  cA64 = -0.071584973281401f, cA65 = -0.028269050394068383f;
__device__ constexpr float cB1 = 0.09646076681806523f,  cB2 = 0.01f,                 cB3 = 0.4798896504144996f;
__device__ constexpr float cB4 = 1.379008574103742f,    cB5 = -3.290069515436081f,   cB6 = 2.324710524099774f;

#define N_D 16
#define N_H 32
#define N_T 40
#define N_B 8192

__device__ __forceinline__ float softplus_f(float x) {
    // jax.nn.softplus = max(x,0) + log1p(exp(-|x|)); fast intrinsics are fine at this threshold
    float e = __expf(-fabsf(x));
    return fmaxf(x, 0.0f) + __logf(1.0f + e);
}

template <int N>
__device__ __forceinline__ float dotN(const float* buf, const float* w, float init) {
    const float4* p = reinterpret_cast<const float4*>(buf);
    float a0 = init, a1 = 0.0f, a2 = 0.0f, a3 = 0.0f;
#pragma unroll
    for (int q = 0; q < N / 4; ++q) {
        float4 u = p[q];
        a0 = fmaf(u.x, w[4 * q + 0], a0);
        a1 = fmaf(u.y, w[4 * q + 1], a1);
        a2 = fmaf(u.z, w[4 * q + 2], a2);
        a3 = fmaf(u.w, w[4 * q + 3], a3);
    }
    return (a0 + a1) + (a2 + a3);
}

// One wave (64 lanes) = 2 trajectories x 32 neurons.
// Lane l: t = l>>5 selects trajectory within block, j = l&31 is the neuron/column index.
// Weights live in per-lane registers (one column per lane); activations are exchanged
// through a 640 B LDS buffer with broadcast ds_read_b128 reads.
__global__ void __launch_bounds__(64) ode_tsit5_kernel(
    const float* __restrict__ x0s, const float* __restrict__ t_eval,
    const float* __restrict__ W0, const float* __restrict__ b0,
    const float* __restrict__ W1, const float* __restrict__ b1,
    const float* __restrict__ W2, const float* __restrict__ b2,
    const float* __restrict__ W3, const float* __restrict__ b3,
    float* __restrict__ out)
{
    __shared__ alignas(16) float ybuf[2][N_D];
    __shared__ alignas(16) float Abuf[2][N_H];
    __shared__ alignas(16) float Bbuf[2][N_H];

    const int l    = threadIdx.x;
    const int t    = l >> 5;
    const int j    = l & 31;
    const int jo   = j & 15;
    const int half = (j >> 4) & 1;
    const int traj = blockIdx.x * 2 + t;

    // Per-lane weight columns (static-indexed after unroll -> registers)
    float w0c[16], w1c[32], w2c[32], w3c[16];
#pragma unroll
    for (int i = 0; i < 16; ++i) w0c[i] = W0[i * N_H + j];
#pragma unroll
    for (int i = 0; i < 32; ++i) w1c[i] = W1[i * N_H + j];
#pragma unroll
    for (int i = 0; i < 32; ++i) w2c[i] = W2[i * N_H + j];
#pragma unroll
    for (int i = 0; i < 16; ++i) w3c[i] = W3[(half * 16 + i) * N_D + jo];
    const float b0j = b0[j], b1j = b1[j], b2j = b2[j], b3j = b3[jo];

    // y and k's duplicated on both 16-lane halves of each trajectory's 32 lanes
    float y = x0s[traj * N_D + jo];

    if (j < 16) {
        ybuf[t][j] = y;
        out[(size_t)traj * N_T * N_D + j] = y;  // SaveAt includes t0
    }

    auto EVAL = [&]() -> float {
        __syncthreads();
        float h = softplus_f(dotN<16>(ybuf[t], w0c, b0j));
        Abuf[t][j] = h;
        __syncthreads();
        h = softplus_f(dotN<32>(Abuf[t], w1c, b1j));
        Bbuf[t][j] = h;
        __syncthreads();
        h = softplus_f(dotN<32>(Bbuf[t], w2c, b2j));
        Abuf[t][j] = h;
        __syncthreads();
        // Output layer: lanes (j, j+16) each sum half the 32 inputs for output dim jo
        float p = dotN<16>(&Abuf[t][half * 16], w3c, 0.0f);
        p += __shfl_xor(p, 16, 64);
        return b3j + p;  // valid on all lanes (duplicated across halves)
    };

    for (int ti = 0; ti < N_T - 1; ++ti) {
        const float dt = (t_eval[ti + 1] - t_eval[ti]) * 0.125f;  // /N_SUB

#pragma unroll 1
        for (int s = 0; s < 8; ++s) {
            const float k1 = EVAL();
            {
                float acc = cA21 * k1;
                float ys  = fmaf(dt, acc, y);
                if (j < 16) ybuf[t][j] = ys;
            }
            const float k2 = EVAL();
            {
                float acc = cA31 * k1;
                acc = fmaf(cA32, k2, acc);
                float ys = fmaf(dt, acc, y);
                if (j < 16) ybuf[t][j] = ys;
            }
            const float k3 = EVAL();
            {
                float acc = cA41 * k1;
                acc = fmaf(cA42, k2, acc);
                acc = fmaf(cA43, k3, acc);
                float ys = fmaf(dt, acc, y);
                if (j < 16) ybuf[t][j] = ys;
            }
            const float k4 = EVAL();
            {
                float acc = cA51 * k1;
                acc = fmaf(cA52, k2, acc);
                acc = fmaf(cA53, k3, acc);
                acc = fmaf(cA54, k4, acc);
                float ys = fmaf(dt, acc, y);
                if (j < 16) ybuf[t][j] = ys;
            }
            const float k5 = EVAL();
            {
                float acc = cA61 * k1;
                acc = fmaf(cA62, k2, acc);
                acc = fmaf(cA63, k3, acc);
                acc = fmaf(cA64, k4, acc);
                acc = fmaf(cA65, k5, acc);
                float ys = fmaf(dt, acc, y);
                if (j < 16) ybuf[t][j] = ys;
            }
            const float k6 = EVAL();
            {
                float acc = cB1 * k1;
                acc = fmaf(cB2, k2, acc);
                acc = fmaf(cB3, k3, acc);
                acc = fmaf(cB4, k4, acc);
                acc = fmaf(cB5, k5, acc);
                acc = fmaf(cB6, k6, acc);
                y = fmaf(dt, acc, y);
                if (j < 16) ybuf[t][j] = y;
            }
        }
        if (j < 16) out[((size_t)traj * N_T + (ti + 1)) * N_D + j] = y;
    }
}

extern "C" void kernel_launch(void* const* d_in, const int* in_sizes, int n_in,
                              void* d_out, int out_size, void* d_ws, size_t ws_size,
                              hipStream_t stream) {
    const float* x0s    = (const float*)d_in[0];
    const float* t_eval = (const float*)d_in[1];
    const float* W0     = (const float*)d_in[2];
    const float* b0     = (const float*)d_in[3];
    const float* W1     = (const float*)d_in[4];
    const float* b1     = (const float*)d_in[5];
    const float* W2     = (const float*)d_in[6];
    const float* b2     = (const float*)d_in[7];
    const float* W3     = (const float*)d_in[8];
    const float* b3     = (const float*)d_in[9];
    float* out          = (float*)d_out;

    dim3 grid(N_B / 2);  // 2 trajectories per 64-thread (1-wave) block
    dim3 block(64);
    hipLaunchKernelGGL(ode_tsit5_kernel, grid, block, 0, stream,
                       x0s, t_eval, W0, b0, W1, b1, W2, b2, W3, b3, out);
}

// Round 3
// 2621.092 us; speedup vs baseline: 1.1219x; 1.1219x over previous
//
#include <hip/hip_runtime.h>

// Tsit5 coefficients (b7 = 0 -> 6 stages)
__device__ constexpr float cA21 = 0.161f;
__device__ constexpr float cA31 = -0.008480655492356989f, cA32 = 0.335480655492357f;
__device__ constexpr float cA41 = 2.8971530571054935f,  cA42 = -6.359448489975075f,  cA43 = 4.3622954328695815f;
__device__ constexpr float cA51 = 5.325864828439257f,   cA52 = -11.748883564062828f, cA53 = 7.4955393428898365f, cA54 = -0.09249506636175525f;
__device__ constexpr float cA61 = 5.86145544294642f,    cA62 = -12.92096931784711f,  cA63 = 8.159367898576159f,  cA64 = -0.071584973281401f, cA65 = -0.028269050394068383f;
__device__ constexpr float cB1 = 0.09646076681806523f,  cB2 = 0.01f,                 cB3 = 0.4798896504144996f;
__device__ constexpr float cB4 = 1.379008574103742f,    cB5 = -3.290069515436081f,   cB6 = 2.324710524099774f;

#define N_D 16
#define N_H 32
#define N_T 40
#define N_B 8192

// Intra-wave producer->consumer fence: LDS writes complete when lgkmcnt hits 0.
// Single-wave data exchange needs no s_barrier (lockstep wave); the "memory"
// clobber stops the compiler reordering the following ds_reads above it.
__device__ __forceinline__ void wave_fence() {
    asm volatile("s_waitcnt lgkmcnt(0)" ::: "memory");
}

__device__ __forceinline__ float softplus_f(float x) {
    // jax.nn.softplus = max(x,0) + log1p(exp(-|x|))
    float e = __expf(-fabsf(x));
    return fmaxf(x, 0.0f) + __logf(1.0f + e);
}

template <int NV>  // NV = number of float4 chunks
__device__ __forceinline__ float dotv(const float* buf, const float* w) {
    const float4* p = reinterpret_cast<const float4*>(buf);
    float a0 = 0.0f, a1 = 0.0f, a2 = 0.0f, a3 = 0.0f;
#pragma unroll
    for (int q = 0; q < NV; ++q) {
        float4 u = p[q];
        a0 = fmaf(u.x, w[4 * q + 0], a0);
        a1 = fmaf(u.y, w[4 * q + 1], a1);
        a2 = fmaf(u.z, w[4 * q + 2], a2);
        a3 = fmaf(u.w, w[4 * q + 3], a3);
    }
    return (a0 + a1) + (a2 + a3);
}

// Wave = 64 lanes = 2 trajectories x 32 neurons, but each lane stores only HALF
// of each weight column (its t-half of the rows) and computes partial dots for
// BOTH trajectories; one shfl_xor(32) completes both. 48 weight regs/lane
// (vs 96 before, which overflowed the register budget -> AGPR/remat bloat).
// Block = 4 independent waves (no __syncthreads anywhere).
__global__ void __launch_bounds__(256) ode_tsit5_kernel(
    const float* __restrict__ x0s, const float* __restrict__ t_eval,
    const float* __restrict__ W0, const float* __restrict__ b0,
    const float* __restrict__ W1, const float* __restrict__ b1,
    const float* __restrict__ W2, const float* __restrict__ b2,
    const float* __restrict__ W3, const float* __restrict__ b3,
    float* __restrict__ out)
{
    __shared__ alignas(16) float ybuf[4][2][N_D];
    __shared__ alignas(16) float Abuf[4][2][N_H];
    __shared__ alignas(16) float Bbuf[4][2][N_H];

    const int tid  = threadIdx.x;
    const int wid  = tid >> 6;
    const int lane = tid & 63;
    const int t    = lane >> 5;   // which trajectory of the wave's pair this lane's weights serve
    const int j    = lane & 31;   // neuron / column index
    const int o    = j & 15;      // output dim (layer 3) / state dim
    const int h    = j >> 4;      // which 16-row half of W3 this lane covers
    const int traj = (blockIdx.x * 4 + wid) * 2 + t;

    float (*yb)[N_D] = ybuf[wid];
    float (*Ab)[N_H] = Abuf[wid];
    float (*Bb)[N_H] = Bbuf[wid];

    // Per-lane HALF weight columns (static-indexed after unroll -> registers)
    float w0c[8], w1c[16], w2c[16], w3c[8];
#pragma unroll
    for (int i = 0; i < 8; ++i)  w0c[i] = W0[(t * 8 + i) * N_H + j];
#pragma unroll
    for (int i = 0; i < 16; ++i) w1c[i] = W1[(t * 16 + i) * N_H + j];
#pragma unroll
    for (int i = 0; i < 16; ++i) w2c[i] = W2[(t * 16 + i) * N_H + j];
#pragma unroll
    for (int i = 0; i < 8; ++i)  w3c[i] = W3[(h * 16 + t * 8 + i) * N_D + o];
    const float b0j = b0[j], b1j = b1[j], b2j = b2[j], b3o = b3[o];

    float y = x0s[traj * N_D + o];

    if (j < 16) {
        yb[t][j] = y;
        out[(size_t)traj * N_T * N_D + j] = y;  // SaveAt includes t0
    }

    // Exchange pattern: lane computes partials p0 (traj 0) and p1 (traj 1) over
    // its rows; sends the partner-trajectory partial, keeps its own, adds the
    // received complement -> full dot for trajectory t on this lane.
    auto EVAL = [&]() -> float {
        wave_fence();  // ybuf writes from previous stage visible
        // L0: D=16 -> H=32, rows [t*8, t*8+8)
        float p0 = dotv<2>(&yb[0][t * 8], w0c);
        float p1 = dotv<2>(&yb[1][t * 8], w0c);
        float send = t ? p0 : p1;
        float keep = t ? p1 : p0;
        float z = keep + __shfl_xor(send, 32, 64) + b0j;
        Ab[t][j] = softplus_f(z);
        wave_fence();
        // L1: 32 -> 32, rows [t*16, t*16+16)
        p0 = dotv<4>(&Ab[0][t * 16], w1c);
        p1 = dotv<4>(&Ab[1][t * 16], w1c);
        send = t ? p0 : p1;
        keep = t ? p1 : p0;
        z = keep + __shfl_xor(send, 32, 64) + b1j;
        Bb[t][j] = softplus_f(z);
        wave_fence();
        // L2: 32 -> 32
        p0 = dotv<4>(&Bb[0][t * 16], w2c);
        p1 = dotv<4>(&Bb[1][t * 16], w2c);
        send = t ? p0 : p1;
        keep = t ? p1 : p0;
        z = keep + __shfl_xor(send, 32, 64) + b2j;
        Ab[t][j] = softplus_f(z);
        wave_fence();
        // L3: 32 -> D=16, rows [h*16 + t*8, +8); combine t-pieces then h-pieces
        p0 = dotv<2>(&Ab[0][h * 16 + t * 8], w3c);
        p1 = dotv<2>(&Ab[1][h * 16 + t * 8], w3c);
        send = t ? p0 : p1;
        keep = t ? p1 : p0;
        float S = keep + __shfl_xor(send, 32, 64);  // my traj, both t-pieces of my h-half
        return S + __shfl_xor(S, 16, 64) + b3o;     // + other h-half (partner shares t)
    };

    for (int ti = 0; ti < N_T - 1; ++ti) {
        const float dt = (t_eval[ti + 1] - t_eval[ti]) * 0.125f;  // / N_SUB

#pragma unroll 1
        for (int s = 0; s < 8; ++s) {
            const float k1 = EVAL();
            {
                float acc = cA21 * k1;
                float ys  = fmaf(dt, acc, y);
                if (j < 16) yb[t][j] = ys;
            }
            const float k2 = EVAL();
            {
                float acc = cA31 * k1;
                acc = fmaf(cA32, k2, acc);
                float ys = fmaf(dt, acc, y);
                if (j < 16) yb[t][j] = ys;
            }
            const float k3 = EVAL();
            {
                float acc = cA41 * k1;
                acc = fmaf(cA42, k2, acc);
                acc = fmaf(cA43, k3, acc);
                float ys = fmaf(dt, acc, y);
                if (j < 16) yb[t][j] = ys;
            }
            const float k4 = EVAL();
            {
                float acc = cA51 * k1;
                acc = fmaf(cA52, k2, acc);
                acc = fmaf(cA53, k3, acc);
                acc = fmaf(cA54, k4, acc);
                float ys = fmaf(dt, acc, y);
                if (j < 16) yb[t][j] = ys;
            }
            const float k5 = EVAL();
            {
                float acc = cA61 * k1;
                acc = fmaf(cA62, k2, acc);
                acc = fmaf(cA63, k3, acc);
                acc = fmaf(cA64, k4, acc);
                acc = fmaf(cA65, k5, acc);
                float ys = fmaf(dt, acc, y);
                if (j < 16) yb[t][j] = ys;
            }
            const float k6 = EVAL();
            {
                float acc = cB1 * k1;
                acc = fmaf(cB2, k2, acc);
                acc = fmaf(cB3, k3, acc);
                acc = fmaf(cB4, k4, acc);
                acc = fmaf(cB5, k5, acc);
                acc = fmaf(cB6, k6, acc);
                y = fmaf(dt, acc, y);
                if (j < 16) yb[t][j] = y;
            }
        }
        if (j < 16) out[((size_t)traj * N_T + (ti + 1)) * N_D + j] = y;
    }
}

extern "C" void kernel_launch(void* const* d_in, const int* in_sizes, int n_in,
                              void* d_out, int out_size, void* d_ws, size_t ws_size,
                              hipStream_t stream) {
    const float* x0s    = (const float*)d_in[0];
    const float* t_eval = (const float*)d_in[1];
    const float* W0     = (const float*)d_in[2];
    const float* b0     = (const float*)d_in[3];
    const float* W1     = (const float*)d_in[4];
    const float* b1     = (const float*)d_in[5];
    const float* W2     = (const float*)d_in[6];
    const float* b2     = (const float*)d_in[7];
    const float* W3     = (const float*)d_in[8];
    const float* b3     = (const float*)d_in[9];
    float* out          = (float*)d_out;

    dim3 grid(N_B / 8);   // 4 waves/block x 2 trajectories/wave
    dim3 block(256);
    hipLaunchKernelGGL(ode_tsit5_kernel, grid, block, 0, stream,
                       x0s, t_eval, W0, b0, W1, b1, W2, b2, W3, b3, out);
}